// Round 4
// baseline (101.189 us; speedup 1.0000x reference)
//
#include <hip/hip_runtime.h>
#include <math.h>

#define BN 16
#define DN 2048
#define ADA 1024
#define INTER 1024
#define NW2 32768   // D*RANK*2
#define HALFN 16384

typedef __attribute__((ext_vector_type(8))) short short8_t;
typedef __attribute__((ext_vector_type(8))) unsigned short ushort8_t;
typedef __attribute__((ext_vector_type(4))) float f32x4;

__device__ inline unsigned short f2bf(float f) {      // fp32 -> bf16 RNE
    unsigned int u = __float_as_uint(f);
    u += 0x7FFFu + ((u >> 16) & 1u);
    return (unsigned short)(u >> 16);
}

// ===========================================================================
// K1a: h_pre[m][j] += sum over k-chunk of ada[m][k]*w1[k][j]   (atomic k-split)
__global__ void k1a(const float* __restrict__ ada, const float* __restrict__ w1,
                    float* __restrict__ h_pre) {
    const int j  = blockIdx.x * 256 + threadIdx.x;
    const int k0 = blockIdx.y * 32;
    __shared__ float a_lds[BN][32];
    for (int idx = threadIdx.x; idx < BN * 32; idx += 256) {
        int m = idx >> 5, kk = idx & 31;
        a_lds[m][kk] = ada[m * ADA + k0 + kk];
    }
    __syncthreads();
    float acc[BN];
#pragma unroll
    for (int m = 0; m < BN; ++m) acc[m] = 0.f;
    for (int kk = 0; kk < 32; ++kk) {
        float w = w1[(k0 + kk) * INTER + j];
#pragma unroll
        for (int m = 0; m < BN; ++m) acc[m] += a_lds[m][kk] * w;
    }
#pragma unroll
    for (int m = 0; m < BN; ++m) atomicAdd(&h_pre[m * INTER + j], acc[m]);
}

// ===========================================================================
// K1b-frag: gelu, then store h in MFMA A-fragment order (bf16):
//   for k-chunk ck (32 k's), lane l, elem j:  value = h[32*ck + 8*(l>>4)+j][l&15]
__global__ void k1bf(const float* __restrict__ h_pre, const float* __restrict__ b1,
                     unsigned short* __restrict__ h_frag) {
    int i = blockIdx.x * 256 + threadIdx.x;     // 16384 elements, i = m*1024 + k
    int m = i >> 10, k = i & (INTER - 1);
    float v = h_pre[i] + b1[k];
    float g = 0.5f * v * (1.f + erff(v * 0.70710678118654752f));
    int ck = k >> 5;
    int l  = ((k >> 3) & 3) * 16 + m;
    int j  = k & 7;
    h_frag[((ck * 64 + l) << 3) + j] = f2bf(g);
}

// ===========================================================================
// K2mfma: p2[kb][m][n] = sum_{k in 256-chunk} h[k][m] * w2[k][n]  via MFMA.
// grid (128, 4), block 256 (4 waves). n-tile 256/block, 64/wave (4 subtiles).
// A (h) frags: 8 per block, held in registers (zero inner-loop h traffic).
// B (w2): fp32 global -> bf16 -> LDS [256 n][40 ushort] (pad to stride 80 B),
//         double-buffered, one barrier per 32-k chunk.
__global__ __launch_bounds__(256) void k2mfma(const unsigned short* __restrict__ h_frag,
                                              const float* __restrict__ w2,
                                              float* __restrict__ p2) {
    const int t    = threadIdx.x;
    const int lane = t & 63;
    const int w    = t >> 6;
    const int n0   = blockIdx.x * 256;
    const int kb   = blockIdx.y;                 // 0..3, k-range kb*256..+256
    __shared__ __align__(16) unsigned short smem[2][256][40];

    // A fragments: chunk ck = kb*8 + c, lane-contiguous 16 B, L2-hot.
    short8_t afr[8];
#pragma unroll
    for (int c = 0; c < 8; ++c)
        afr[c] = *reinterpret_cast<const short8_t*>(
            h_frag + (((kb * 8 + c) * 64 + lane) << 3));

    f32x4 acc[4];
#pragma unroll
    for (int i = 0; i < 4; ++i) acc[i] = (f32x4){0.f, 0.f, 0.f, 0.f};

    // w2 column stream: thread t owns column n0+t; 32 rows per chunk.
    const float* wbase = w2 + (size_t)(kb * 256) * NW2 + n0 + t;
    float wreg[32];
#pragma unroll
    for (int kk = 0; kk < 32; ++kk) wreg[kk] = wbase[(size_t)kk * NW2];

    for (int c = 0; c < 8; ++c) {
        const int cur = c & 1;
        // pack chunk c to LDS row t (4x ushort8 = 64 B data + 16 B pad)
        unsigned short* row = &smem[cur][t][0];
#pragma unroll
        for (int q = 0; q < 4; ++q) {
            ushort8_t v;
#pragma unroll
            for (int e = 0; e < 8; ++e) v[e] = f2bf(wreg[q * 8 + e]);
            *reinterpret_cast<ushort8_t*>(row + q * 8) = v;
        }
        if (c < 7) {                              // issue next chunk's loads
            const float* wn = wbase + (size_t)((c + 1) * 32) * NW2;
#pragma unroll
            for (int kk = 0; kk < 32; ++kk) wreg[kk] = wn[(size_t)kk * NW2];
        }
        __syncthreads();                          // writes(cur) visible; reads(c-2) done
#pragma unroll
        for (int i = 0; i < 4; ++i) {
            const short8_t b = *reinterpret_cast<const short8_t*>(
                &smem[cur][(w * 4 + i) * 16 + (lane & 15)][(lane >> 4) * 8]);
            acc[i] = __builtin_amdgcn_mfma_f32_16x16x32_bf16(afr[c], b, acc[i], 0, 0, 0);
        }
    }

    // D layout (m89-verified): col = lane&15, row = (lane>>4)*4 + r
    float* op = p2 + (size_t)kb * (BN * NW2);
#pragma unroll
    for (int i = 0; i < 4; ++i) {
        const int n = n0 + (w * 4 + i) * 16 + (lane & 15);
#pragma unroll
        for (int r = 0; r < 4; ++r) {
            const int m = (lane >> 4) * 4 + r;
            op[(size_t)m * NW2 + n] = acc[i][r];
        }
    }
}

// ===========================================================================
// K2r: xw[m][n] = b2[n] + sum_{ks<4} p2[ks][m][n]    (float4, coalesced)
__global__ void k2r(const float* __restrict__ p2, const float* __restrict__ b2,
                    float* __restrict__ xw) {
    const int i  = blockIdx.x * 256 + threadIdx.x;  // float4 idx over 131072
    const int n4 = i & (NW2 / 4 - 1);
    float4 s = ((const float4*)b2)[n4];
    const float4* p = (const float4*)p2 + i;
#pragma unroll
    for (int ks = 0; ks < 4; ++ks) {
        float4 v = p[(size_t)ks * (BN * NW2 / 4)];
        s.x += v.x; s.y += v.y; s.z += v.z; s.w += v.w;
    }
    ((float4*)xw)[i] = s;
}

// ===========================================================================
// K3: t[m][r] = sum_c x[m][c] * xw[m][c*8+r]   (x_a half)
__global__ void k3(const float* __restrict__ x, const float* __restrict__ xw,
                   float* __restrict__ t) {
    const int m = blockIdx.x >> 3, r = blockIdx.x & 7;
    float s = 0.f;
    for (int c = threadIdx.x; c < DN; c += 256)
        s += x[m * DN + c] * xw[(size_t)m * NW2 + c * 8 + r];
    __shared__ float red[256];
    red[threadIdx.x] = s;
    __syncthreads();
    for (int off = 128; off > 0; off >>= 1) {
        if (threadIdx.x < off) red[threadIdx.x] += red[threadIdx.x + off];
        __syncthreads();
    }
    if (threadIdx.x == 0) t[m * 8 + r] = red[0];
}

// ===========================================================================
// K4m: p4[cs][m][o] = sum_{c in 32-chunk} x[m][c] * base[c][o]
// grid (2, 64, 2), block 256. Thread owns float4 of o for 8 m; no LDS.
#define K4ACC(i, xv) do { acc[i].x = fmaf((xv), b.x, acc[i].x); \
                          acc[i].y = fmaf((xv), b.y, acc[i].y); \
                          acc[i].z = fmaf((xv), b.z, acc[i].z); \
                          acc[i].w = fmaf((xv), b.w, acc[i].w); } while (0)
__global__ __launch_bounds__(256) void k4m(const float* __restrict__ x,
                                           const float* __restrict__ base,
                                           float* __restrict__ p4) {
    const int o4 = blockIdx.x * 256 + threadIdx.x;   // [0, 512)
    const int c0 = blockIdx.y * 32;
    const int m0 = blockIdx.z * 8;
    float4 acc[8];
#pragma unroll
    for (int m = 0; m < 8; ++m) acc[m] = make_float4(0.f, 0.f, 0.f, 0.f);

    const float4* bp = (const float4*)base + (size_t)c0 * (DN / 4) + o4;
    float4 bbuf[8];
#pragma unroll
    for (int u = 0; u < 8; ++u) bbuf[u] = bp[(size_t)u * (DN / 4)];

    for (int cb = 0; cb < 32; cb += 8) {
#pragma unroll
        for (int u = 0; u < 8; ++u) {
            const int cc = cb + u;
            const float4 b = bbuf[u];
            const int cn = (cc + 8 < 32) ? (cc + 8) : cc;    // uniform clamp
            bbuf[u] = bp[(size_t)cn * (DN / 4)];
            const float x0 = x[(m0 + 0) * DN + c0 + cc];
            const float x1 = x[(m0 + 1) * DN + c0 + cc];
            const float x2 = x[(m0 + 2) * DN + c0 + cc];
            const float x3 = x[(m0 + 3) * DN + c0 + cc];
            const float x4 = x[(m0 + 4) * DN + c0 + cc];
            const float x5 = x[(m0 + 5) * DN + c0 + cc];
            const float x6 = x[(m0 + 6) * DN + c0 + cc];
            const float x7 = x[(m0 + 7) * DN + c0 + cc];
            K4ACC(0, x0); K4ACC(1, x1); K4ACC(2, x2); K4ACC(3, x3);
            K4ACC(4, x4); K4ACC(5, x5); K4ACC(6, x6); K4ACC(7, x7);
        }
    }
    float4* op = (float4*)p4 + (size_t)blockIdx.y * (BN * DN / 4)
               + (size_t)m0 * (DN / 4) + o4;
#pragma unroll
    for (int m = 0; m < 8; ++m) op[(size_t)m * (DN / 4)] = acc[m];
}

// ===========================================================================
// K5: out[m][o] = x[m][o] + sum_{cs<64} p4[cs][m][o] + sum_r t[m][r]*x_b[m][o][r]
__global__ void k5(const float* __restrict__ x, const float* __restrict__ p4,
                   const float* __restrict__ xw, const float* __restrict__ t,
                   float* __restrict__ out) {
    const int i = blockIdx.x * 256 + threadIdx.x;   // [0, 32768)
    const int m = i >> 11, o = i & (DN - 1);
    float s = x[i];
    const float* p = p4 + i;
#pragma unroll 8
    for (int ks = 0; ks < 64; ++ks) s += p[ks * (BN * DN)];
    const float4 xb0 = *(const float4*)(xw + (size_t)m * NW2 + HALFN + o * 8);
    const float4 xb1 = *(const float4*)(xw + (size_t)m * NW2 + HALFN + o * 8 + 4);
    const float* tm = t + m * 8;
    s += tm[0] * xb0.x + tm[1] * xb0.y + tm[2] * xb0.z + tm[3] * xb0.w
       + tm[4] * xb1.x + tm[5] * xb1.y + tm[6] * xb1.z + tm[7] * xb1.w;
    out[i] = s;
}

// ===========================================================================
extern "C" void kernel_launch(void* const* d_in, const int* in_sizes, int n_in,
                              void* d_out, int out_size, void* d_ws, size_t ws_size,
                              hipStream_t stream) {
    const float* x    = (const float*)d_in[0];
    const float* ada  = (const float*)d_in[1];
    const float* base = (const float*)d_in[2];
    const float* w1   = (const float*)d_in[3];
    const float* b1   = (const float*)d_in[4];
    const float* w2   = (const float*)d_in[5];
    const float* b2   = (const float*)d_in[6];
    float* out = (float*)d_out;
    char* ws = (char*)d_ws;

    // ws layout (bytes):
    //   p2     @ 0           (4 * 16*32768*4 = 8,388,608)
    //   xw     @ 8,388,608   (2,097,152)
    //   p4     @ 10,485,760  (64 * 16*2048*4 = 8,388,608)
    //   h_pre  @ 18,874,368  (65,536)
    //   h_frag @ 18,939,904  (32,768)
    //   t      @ 18,972,672  (512)
    float*          p2     = (float*)(ws);
    float*          xw     = (float*)(ws + 8388608);
    float*          p4     = (float*)(ws + 10485760);
    float*          h_pre  = (float*)(ws + 18874368);
    unsigned short* h_frag = (unsigned short*)(ws + 18939904);
    float*          t      = (float*)(ws + 18972672);

    hipMemsetAsync(h_pre, 0, 65536, stream);   // k1a atomic accumulator only

    k1a   <<<dim3(4, 32),    256, 0, stream>>>(ada, w1, h_pre);
    k1bf  <<<64,             256, 0, stream>>>(h_pre, b1, h_frag);
    k2mfma<<<dim3(128, 4),   256, 0, stream>>>(h_frag, w2, p2);
    k4m   <<<dim3(2, 64, 2), 256, 0, stream>>>(x, base, p4);
    k2r   <<<512,            256, 0, stream>>>(p2, b2, xw);
    k3    <<<128,            256, 0, stream>>>(x, xw, t);
    k5    <<<128,            256, 0, stream>>>(x, p4, xw, t, out);
}